// Round 6
// baseline (211.870 us; speedup 1.0000x reference)
//
#include <hip/hip_runtime.h>
#include <hip/hip_bf16.h>

// Problem constants: B=8, S=1024, E=1024, H=16, D=64
#define PB 8
#define PS 1024
#define PE 1024
#define PH 16
#define PD 64
#define EPSLN 1e-3f
#define SCALE 0.03125f   // E^-0.5 = 1/32 (full emb, faithful to reference)

typedef __attribute__((ext_vector_type(8))) short bf16x8;    // 8 bf16 = 4 VGPR
typedef __attribute__((ext_vector_type(4))) float f32x4;
typedef __attribute__((ext_vector_type(16))) float f32x16;

__device__ __forceinline__ unsigned short f2bf(float f) {
    unsigned int u = __float_as_uint(f);
    u += 0x7FFFu + ((u >> 16) & 1u);   // RNE
    return (unsigned short)(u >> 16);
}

__device__ __forceinline__ void gload_lds16(const void* g, void* l) {
    __builtin_amdgcn_global_load_lds(
        (const __attribute__((address_space(1))) unsigned int*)g,
        (__attribute__((address_space(3))) unsigned int*)l,
        16, 0, 0);
}

__device__ __forceinline__ unsigned int cvtpk_bf16(float lo, float hi) {
    unsigned int r;
    asm("v_cvt_pk_bf16_f32 %0, %1, %2" : "=v"(r) : "v"(lo), "v"(hi));
    return r;
}

__device__ __forceinline__ void plswap(unsigned int& a, unsigned int& b) {
    asm("v_permlane32_swap_b32 %0, %1" : "+v"(a), "+v"(b));
}

// LDS chunk swizzle: slot(row, chunk) — measured 0 conflicts (r5).
#define SWZF(row, chunk) (((chunk) ^ ((row) & 7) ^ (((row) >> 3) & 3)))

// ---------------------------------------------------------------------------
// Convert X f32 -> bf16 (8M elems, 8 per thread)
// ---------------------------------------------------------------------------
__global__ __launch_bounds__(256) void conv_x(
    const float* __restrict__ X, unsigned short* __restrict__ Xb)
{
    const size_t i = (size_t)blockIdx.x * 256 + threadIdx.x;
    const float4* p = reinterpret_cast<const float4*>(X) + i * 2;
    float4 a = p[0], b = p[1];
    unsigned short r[8];
    r[0] = f2bf(a.x); r[1] = f2bf(a.y); r[2] = f2bf(a.z); r[3] = f2bf(a.w);
    r[4] = f2bf(b.x); r[5] = f2bf(b.y); r[6] = f2bf(b.z); r[7] = f2bf(b.w);
    *reinterpret_cast<uint4*>(Xb + i * 8) = *reinterpret_cast<const uint4*>(r);
}

// ---------------------------------------------------------------------------
// Transpose+convert W's: Wtb[proj*1024 + n][k] = W_proj[k][n] as bf16
// ---------------------------------------------------------------------------
__global__ __launch_bounds__(256) void conv_w(
    const float* __restrict__ Wq, const float* __restrict__ Wk,
    const float* __restrict__ Wv, unsigned short* __restrict__ Wtb)
{
    const int proj = blockIdx.z;
    const float* W = (proj == 0) ? Wq : (proj == 1) ? Wk : Wv;
    __shared__ float tile[32][33];
    const int n0 = blockIdx.x * 32, k0 = blockIdx.y * 32;
    const int tx = threadIdx.x & 31, ty = threadIdx.x >> 5;  // 32 x 8
#pragma unroll
    for (int i = 0; i < 4; ++i)
        tile[ty + i * 8][tx] = W[(size_t)(k0 + ty + i * 8) * PE + n0 + tx];
    __syncthreads();
#pragma unroll
    for (int i = 0; i < 4; ++i)
        Wtb[(size_t)(proj * 1024 + n0 + ty + i * 8) * 1024 + k0 + tx] =
            f2bf(tile[tx][ty + i * 8]);
}

// ---------------------------------------------------------------------------
// rel f32 -> bf16 table (2047 x 16)
// ---------------------------------------------------------------------------
__global__ __launch_bounds__(256) void conv_rel(
    const float* __restrict__ rel, unsigned short* __restrict__ relbf)
{
    const int i = blockIdx.x * 1024 + threadIdx.x * 4;
#pragma unroll
    for (int k = 0; k < 4; ++k)
        if (i + k < (2 * PS - 1) * PH) relbf[i + k] = f2bf(rel[i + k]);
}

// ---------------------------------------------------------------------------
// QKV GEMM: C[8192][3072] bf16 = Xb[8192][1024] @ Wtb^T, MFMA 16x16x32 bf16.
// 256x256 tile, BK=64, 8 waves (2x4), 512 threads, LDS 128KB double-buffered.
// Pipelined: per K-tile 4 phases {p1/p2: all 24 frag ds_reads -> regs + q0/q1
// MFMA; barrier; p3/p4: stage K-tile k+2 into the now-dead buffer + q2/q3}.
// Counted vmcnt(8) at tile entry (16 loads in flight steady-state, never 0).
// ---------------------------------------------------------------------------
__global__ __launch_bounds__(512, 2) void qkv_mfma(
    const unsigned short* __restrict__ Xb,
    const unsigned short* __restrict__ Wtb,
    unsigned short* __restrict__ QKV)
{
    // 384 blocks = 8 XCD-chunks of 48; bijective (384 % 8 == 0)
    const int orig = blockIdx.x;
    const int wg = (orig & 7) * 48 + (orig >> 3);
    const int nblk = wg % 12, mblk = wg / 12;
    const int m0 = mblk * 256, n0 = nblk * 256;

    __shared__ __align__(16) unsigned short As[2][256 * 64];  // 64 KB
    __shared__ __align__(16) unsigned short Bs[2][256 * 64];  // 64 KB

    const int t = threadIdx.x;              // 0..511
    const int l = t & 63, w = t >> 6;       // 8 waves
    const int lane15 = l & 15, lhi = l >> 4;
    const int wm = w >> 2, wn = w & 3;      // 2 x 4 wave grid

    f32x4 acc[8][4] = {};                   // 128 VGPR accumulator

    // stage one operand tile (32 KB = 4 loads/thread) of K-tile kt into buf c
#define QSTAGE_A(kt, c)                                                         \
    {                                                                           \
        _Pragma("unroll")                                                       \
        for (int rr = 0; rr < 4; ++rr) {                                        \
            const int ci = rr * 512 + t;                                        \
            const int r = ci >> 3;                                              \
            const int scl = SWZF(r, ci & 7);                                    \
            gload_lds16(Xb + (size_t)(m0 + r) * 1024 + (kt) * 64 + scl * 8,     \
                        &As[c][ci * 8]);                                        \
        }                                                                       \
    }
#define QSTAGE_B(kt, c)                                                         \
    {                                                                           \
        _Pragma("unroll")                                                       \
        for (int rr = 0; rr < 4; ++rr) {                                        \
            const int ci = rr * 512 + t;                                        \
            const int r = ci >> 3;                                              \
            const int scl = SWZF(r, ci & 7);                                    \
            gload_lds16(Wtb + (size_t)(n0 + r) * 1024 + (kt) * 64 + scl * 8,    \
                        &Bs[c][ci * 8]);                                        \
        }                                                                       \
    }

    // prologue: tiles 0 and 1 (16 loads/thread in flight)
    QSTAGE_A(0, 0) QSTAGE_B(0, 0)
    QSTAGE_A(1, 1) QSTAGE_B(1, 1)

    for (int kt = 0; kt < 16; ++kt) {
        const int c = kt & 1;
        // Stage(kt) landed: oldest 8 of 16 outstanding loads complete.
        if (kt < 14) { asm volatile("s_waitcnt vmcnt(8)" ::: "memory"); }
        else         { asm volatile("s_waitcnt vmcnt(0)" ::: "memory"); }
        __builtin_amdgcn_sched_barrier(0);
        __builtin_amdgcn_s_barrier();       // B1: every wave's stage landed
        __builtin_amdgcn_sched_barrier(0);

        bf16x8 af[8][2], bf[4][2];
        // ---- p1: frag reads (A mi0-3, B ni0-1) + MFMA q0 ----
#pragma unroll
        for (int mi = 0; mi < 4; ++mi)
#pragma unroll
            for (int kk = 0; kk < 2; ++kk) {
                const int row = wm * 128 + mi * 16 + lane15;
                af[mi][kk] = *reinterpret_cast<const bf16x8*>(
                    &As[c][row * 64 + (SWZF(row, kk * 4 + lhi) << 3)]);
            }
#pragma unroll
        for (int ni = 0; ni < 2; ++ni)
#pragma unroll
            for (int kk = 0; kk < 2; ++kk) {
                const int row = wn * 64 + ni * 16 + lane15;
                bf[ni][kk] = *reinterpret_cast<const bf16x8*>(
                    &Bs[c][row * 64 + (SWZF(row, kk * 4 + lhi) << 3)]);
            }
        asm volatile("s_waitcnt lgkmcnt(0)" ::: "memory");
        __builtin_amdgcn_sched_barrier(0);
        __builtin_amdgcn_s_setprio(1);
#pragma unroll
        for (int mi = 0; mi < 4; ++mi)
#pragma unroll
            for (int ni = 0; ni < 2; ++ni)
#pragma unroll
                for (int kk = 0; kk < 2; ++kk)
                    acc[mi][ni] = __builtin_amdgcn_mfma_f32_16x16x32_bf16(
                        af[mi][kk], bf[ni][kk], acc[mi][ni], 0, 0, 0);
        __builtin_amdgcn_s_setprio(0);

        // ---- p2: frag reads (A mi4-7, B ni2-3) + MFMA q1 ----
#pragma unroll
        for (int mi = 4; mi < 8; ++mi)
#pragma unroll
            for (int kk = 0; kk < 2; ++kk) {
                const int row = wm * 128 + mi * 16 + lane15;
                af[mi][kk] = *reinterpret_cast<const bf16x8*>(
                    &As[c][row * 64 + (SWZF(row, kk * 4 + lhi) << 3)]);
            }
#pragma unroll
        for (int ni = 2; ni < 4; ++ni)
#pragma unroll
            for (int kk = 0; kk < 2; ++kk) {
                const int row = wn * 64 + ni * 16 + lane15;
                bf[ni][kk] = *reinterpret_cast<const bf16x8*>(
                    &Bs[c][row * 64 + (SWZF(row, kk * 4 + lhi) << 3)]);
            }
        asm volatile("s_waitcnt lgkmcnt(0)" ::: "memory");
        __builtin_amdgcn_sched_barrier(0);
        __builtin_amdgcn_s_setprio(1);
#pragma unroll
        for (int mi = 0; mi < 4; ++mi)
#pragma unroll
            for (int ni = 2; ni < 4; ++ni)
#pragma unroll
                for (int kk = 0; kk < 2; ++kk)
                    acc[mi][ni] = __builtin_amdgcn_mfma_f32_16x16x32_bf16(
                        af[mi][kk], bf[ni][kk], acc[mi][ni], 0, 0, 0);
        __builtin_amdgcn_s_setprio(0);
        __builtin_amdgcn_sched_barrier(0);
        __builtin_amdgcn_s_barrier();       // B2: buf c fully read into regs
        __builtin_amdgcn_sched_barrier(0);

        // ---- p3: stage A(kt+2) into buf c + MFMA q2 ----
        if (kt < 14) { QSTAGE_A(kt + 2, c) }
        __builtin_amdgcn_s_setprio(1);
#pragma unroll
        for (int mi = 4; mi < 8; ++mi)
#pragma unroll
            for (int ni = 0; ni < 2; ++ni)
#pragma unroll
                for (int kk = 0; kk < 2; ++kk)
                    acc[mi][ni] = __builtin_amdgcn_mfma_f32_16x16x32_bf16(
                        af[mi][kk], bf[ni][kk], acc[mi][ni], 0, 0, 0);
        __builtin_amdgcn_s_setprio(0);

        // ---- p4: stage B(kt+2) into buf c + MFMA q3 ----
        if (kt < 14) { QSTAGE_B(kt + 2, c) }
        __builtin_amdgcn_s_setprio(1);
#pragma unroll
        for (int mi = 4; mi < 8; ++mi)
#pragma unroll
            for (int ni = 2; ni < 4; ++ni)
#pragma unroll
                for (int kk = 0; kk < 2; ++kk)
                    acc[mi][ni] = __builtin_amdgcn_mfma_f32_16x16x32_bf16(
                        af[mi][kk], bf[ni][kk], acc[mi][ni], 0, 0, 0);
        __builtin_amdgcn_s_setprio(0);
    }
#undef QSTAGE_A
#undef QSTAGE_B

#pragma unroll
    for (int mi = 0; mi < 8; ++mi)
#pragma unroll
        for (int ni = 0; ni < 4; ++ni)
#pragma unroll
            for (int r = 0; r < 4; ++r) {
                const int gr = m0 + wm * 128 + mi * 16 + lhi * 4 + r;
                const int gc = n0 + wn * 64 + ni * 16 + lane15;
                QKV[(size_t)gr * 3072 + gc] = f2bf(acc[mi][ni][r]);
            }
}

// ---------------------------------------------------------------------------
// V transpose: VT[h][b][d][j] = QKV[b*S+j][2048 + h*64 + d]  (bf16, 16 MB)
// ---------------------------------------------------------------------------
__global__ __launch_bounds__(256) void vtrans(
    const unsigned short* __restrict__ QKV, unsigned short* __restrict__ VT)
{
    const int j0 = blockIdx.x * 64, b = blockIdx.y, h = blockIdx.z;
    __shared__ unsigned short tile[64][72];
    const int t = threadIdx.x;

#pragma unroll
    for (int it = 0; it < 2; ++it) {
        const int jr = it * 32 + (t >> 3), dc = t & 7;
        uint4 d = *reinterpret_cast<const uint4*>(
            QKV + ((size_t)(b * PS + j0 + jr)) * 3072 + 2048 + h * 64 + dc * 8);
        *reinterpret_cast<uint4*>(&tile[jr][dc * 8]) = d;
    }
    __syncthreads();
    const int d = t & 63, jc = t >> 6;
    unsigned short out[16];
#pragma unroll
    for (int k = 0; k < 16; ++k) out[k] = tile[jc * 16 + k][d];
    unsigned short* dst = VT + ((size_t)((h * 8 + b) * 64 + d)) * 1024 + j0 + jc * 16;
    *reinterpret_cast<uint4*>(dst)     = *reinterpret_cast<const uint4*>(out);
    *reinterpret_cast<uint4*>(dst + 8) = *reinterpret_cast<const uint4*>(out + 8);
}

// ---------------------------------------------------------------------------
// Fused attention, 32x32x16 MFMA, swapped QK^T, in-register softmax (T12),
// fused bias.V, row-sum via ones-MFMA.  Block = 4 waves x 32 q = 128 q-rows.
// ---------------------------------------------------------------------------
__global__ __launch_bounds__(256) void attn_mfma(
    const unsigned short* __restrict__ qkv,
    const unsigned short* __restrict__ VT,
    const unsigned short* __restrict__ relbf,
    float* __restrict__ O)
{
    __shared__ __align__(16) unsigned short Ks[2][64 * 64];  // [j][d] swizzled
    __shared__ __align__(16) unsigned short Vt[2][64 * 64];  // [d][j] swizzled

    const int orig = blockIdx.x;                   // 1024 blocks
    const int wg = (orig & 7) * 128 + (orig >> 3); // XCD-chunked, bijective
    const int qt = wg & 7;
    const int h  = (wg >> 3) & 15;
    const int b  = wg >> 7;

    const int t = threadIdx.x;
    const int w = t >> 6, l = t & 63;
    const int lane31 = l & 31, hi = l >> 5;

    const int qrow_g = qt * 128 + w * 32 + lane31;   // query index i (0..1023)

    // Q fragments (B-operand of swapped QK): col=q=lane31, k=hi*8+e
    bf16x8 qf[4];
    {
        const unsigned short* qp =
            qkv + ((size_t)(b * PS) + qrow_g) * 3072 + h * 64 + hi * 8;
#pragma unroll
        for (int dw = 0; dw < 4; ++dw)
            qf[dw] = *reinterpret_cast<const bf16x8*>(qp + dw * 16);
    }

    const unsigned short* Kg = qkv + (size_t)(b * PS) * 3072 + 1024 + h * 64;
    const unsigned short* Vg = VT + ((size_t)((h * 8 + b) * 64)) * 1024;

    // hoisted bias-table pointer: af[jw] at tile tt = relp + tt*64 + jw*16
    const int s1 = (h << 6) | (qrow_g >> 4);
    const int s2hi = (qrow_g & 15) << 6;
    const unsigned short* relp = relbf + (size_t)(s2hi - s1 + PS - 1) * PH + hi * 8;

    f32x16 accP[2] = {};
    f32x16 accB[2] = {};
    f32x16 accL = {};
    bf16x8 ones;
#pragma unroll
    for (int i = 0; i < 8; ++i) ones[i] = (short)0x3F80;  // bf16 1.0

#define ATTN_STAGE(buf, j0)                                                          \
    {                                                                                \
        _Pragma("unroll")                                                            \
        for (int it = 0; it < 2; ++it) {                                             \
            const int ci = it * 256 + t;                                             \
            const int r = ci >> 3;                                                   \
            const int scl = SWZF(r, ci & 7);                                         \
            gload_lds16(Kg + (size_t)((j0) + r) * 3072 + scl * 8, &Ks[buf][ci * 8]); \
            gload_lds16(Vg + (size_t)r * 1024 + (j0) + scl * 8, &Vt[buf][ci * 8]);   \
        }                                                                            \
    }

    ATTN_STAGE(0, 0)

    for (int tt = 0; tt < 16; ++tt) {
        const int cur = tt & 1;
        const int j0 = tt * 64;

        // bias A-frags: 16 contiguous bf16 from relbf (L2-resident)
        bf16x8 af[4];
        __builtin_amdgcn_sched_barrier(0);
#pragma unroll
        for (int jw = 0; jw < 4; ++jw)
            af[jw] = *reinterpret_cast<const bf16x8*>(relp + j0 + jw * 16);
        __builtin_amdgcn_sched_barrier(0);
        if (tt < 15) {
            ATTN_STAGE(cur ^ 1, j0 + 64)
            __builtin_amdgcn_sched_barrier(0);
            asm volatile("s_waitcnt vmcnt(8)" ::: "memory");  // cur tile staged
        } else {
            asm volatile("s_waitcnt vmcnt(4)" ::: "memory");
        }
        __builtin_amdgcn_sched_barrier(0);
        __builtin_amdgcn_s_barrier();
        __builtin_amdgcn_sched_barrier(0);

        // --- QK^T (swapped): S^T[j][q], then exp -> P fragments in-register ---
        bf16x8 pfrag[4];
#pragma unroll
        for (int jt = 0; jt < 2; ++jt) {
            f32x16 sc = {};
            __builtin_amdgcn_s_setprio(1);
#pragma unroll
            for (int dw = 0; dw < 4; ++dw) {
                const int row = jt * 32 + lane31;
                bf16x8 aK = *reinterpret_cast<const bf16x8*>(
                    &Ks[cur][row * 64 + (SWZF(row, dw * 2 + hi) << 3)]);
                sc = __builtin_amdgcn_mfma_f32_32x32x16_bf16(aK, qf[dw], sc, 0, 0, 0);
            }
            __builtin_amdgcn_s_setprio(0);
            // lane holds S^T[j = jt*32 + 4*(2*(r>>2)+hi) + (r&3)][q=lane31]
            float p[16];
#pragma unroll
            for (int r = 0; r < 16; ++r) p[r] = __expf(sc[r] * SCALE);  // fixed m=0
            unsigned int a0 = cvtpk_bf16(p[0],  p[1]),  a1 = cvtpk_bf16(p[2],  p[3]);
            unsigned int b0 = cvtpk_bf16(p[4],  p[5]),  b1 = cvtpk_bf16(p[6],  p[7]);
            unsigned int c0 = cvtpk_bf16(p[8],  p[9]),  c1 = cvtpk_bf16(p[10], p[11]);
            unsigned int d0 = cvtpk_bf16(p[12], p[13]), d1 = cvtpk_bf16(p[14], p[15]);
            plswap(a0, b0); plswap(a1, b1);   // win0: quads (2hi, 2hi+1)
            plswap(c0, d0); plswap(c1, d1);   // win1: quads (4+2hi, 5+2hi)
            union { unsigned int u[4]; bf16x8 v; } pk0, pk1;
            pk0.u[0] = a0; pk0.u[1] = a1; pk0.u[2] = b0; pk0.u[3] = b1;
            pk1.u[0] = c0; pk1.u[1] = c1; pk1.u[2] = d0; pk1.u[3] = d1;
            pfrag[jt * 2]     = pk0.v;
            pfrag[jt * 2 + 1] = pk1.v;
        }

        // --- PV + bias.V + row-sum: V fragment loaded once, used by both chains
        __builtin_amdgcn_s_setprio(1);
#pragma unroll
        for (int jw = 0; jw < 4; ++jw) {
            accL = __builtin_amdgcn_mfma_f32_32x32x16_bf16(pfrag[jw], ones, accL, 0, 0, 0);
#pragma unroll
            for (int dt = 0; dt < 2; ++dt) {
                const int row = dt * 32 + lane31;
                bf16x8 bV = *reinterpret_cast<const bf16x8*>(
                    &Vt[cur][row * 64 + (SWZF(row, jw * 2 + hi) << 3)]);
                accP[dt] = __builtin_amdgcn_mfma_f32_32x32x16_bf16(
                    pfrag[jw], bV, accP[dt], 0, 0, 0);
                accB[dt] = __builtin_amdgcn_mfma_f32_32x32x16_bf16(
                    af[jw], bV, accB[dt], 0, 0, 0);
            }
        }
        __builtin_amdgcn_s_setprio(0);
        __builtin_amdgcn_s_barrier();
    }
#undef ATTN_STAGE

    // accL[r] = l[q-row rl] replicated across all lanes of the row's quads
#pragma unroll
    for (int dt = 0; dt < 2; ++dt)
#pragma unroll
        for (int r = 0; r < 16; ++r) {
            const int rl = (r & 3) + 8 * (r >> 2) + 4 * hi;   // q-row local
            O[((size_t)(b * PS + qt * 128 + w * 32 + rl)) * PE + h * 64 + dt * 32 + lane31]
                = accP[dt][r] / accL[r] + accB[dt][r];
        }
}

// ---------------------------------------------------------------------------
// LayerNorm over last dim (1024), in-place on d_out.
// ---------------------------------------------------------------------------
__global__ __launch_bounds__(256) void layernorm_inplace(
    float* __restrict__ O,
    const float* __restrict__ gamma,
    const float* __restrict__ beta)
{
    const int row = blockIdx.x;
    float* p = O + (size_t)row * PE;
    const int t = threadIdx.x;

    float4 x = reinterpret_cast<float4*>(p)[t];
    float s  = x.x + x.y + x.z + x.w;
    float s2 = x.x * x.x + x.y * x.y + x.z * x.z + x.w * x.w;

#pragma unroll
    for (int off = 1; off < 64; off <<= 1) {
        s  += __shfl_xor(s, off, 64);
        s2 += __shfl_xor(s2, off, 64);
    }
    __shared__ float red[2][4];
    const int wid = t >> 6;
    if ((t & 63) == 0) { red[0][wid] = s; red[1][wid] = s2; }
    __syncthreads();
    const float ts  = red[0][0] + red[0][1] + red[0][2] + red[0][3];
    const float ts2 = red[1][0] + red[1][1] + red[1][2] + red[1][3];

    const float mu  = ts * (1.f / PE);
    const float var = ts2 * (1.f / PE) - mu * mu;
    const float inv = rsqrtf(var + EPSLN);

    const float4 g  = reinterpret_cast<const float4*>(gamma)[t];
    const float4 bb = reinterpret_cast<const float4*>(beta)[t];
    float4 y;
    y.x = (x.x - mu) * inv * g.x + bb.x;
    y.y = (x.y - mu) * inv * g.y + bb.y;
    y.z = (x.z - mu) * inv * g.z + bb.z;
    y.w = (x.w - mu) * inv * g.w + bb.w;
    reinterpret_cast<float4*>(p)[t] = y;
}

// ---------------------------------------------------------------------------
extern "C" void kernel_launch(void* const* d_in, const int* in_sizes, int n_in,
                              void* d_out, int out_size, void* d_ws, size_t ws_size,
                              hipStream_t stream) {
    (void)in_sizes; (void)n_in; (void)out_size; (void)ws_size;
    const float* x     = (const float*)d_in[0];
    const float* Wq    = (const float*)d_in[1];
    const float* Wk    = (const float*)d_in[2];
    const float* Wv    = (const float*)d_in[3];
    const float* rel   = (const float*)d_in[4];
    const float* gamma = (const float*)d_in[5];
    const float* beta  = (const float*)d_in[6];
    float* out = (float*)d_out;

    char* ws = (char*)d_ws;
    // Layout (86 MB): [Xb 16MB | Wtb 6MB | QKV 48MB | VT 16MB]
    // relbf (64KB) aliases Xb region: Xb dead after qkv_mfma; conv_rel runs after.
    unsigned short* Xb    = (unsigned short*)ws;
    unsigned short* Wtb   = (unsigned short*)(ws + 16777216);
    unsigned short* QKV   = (unsigned short*)(ws + 23068672);
    unsigned short* VT    = (unsigned short*)(ws + 73400320);
    unsigned short* relbf = (unsigned short*)ws;

    conv_x<<<4096, 256, 0, stream>>>(x, Xb);
    conv_w<<<dim3(32, 32, 3), 256, 0, stream>>>(Wq, Wk, Wv, Wtb);
    qkv_mfma<<<384, 512, 0, stream>>>(Xb, Wtb, QKV);
    conv_rel<<<32, 256, 0, stream>>>(rel, relbf);
    vtrans<<<dim3(16, 8, 16), 256, 0, stream>>>(QKV, VT);
    attn_mfma<<<1024, 256, 0, stream>>>(QKV, VT, relbf, out);
    layernorm_inplace<<<PB * PS, 256, 0, stream>>>(out, gamma, beta);
}

// Round 7
// 181.536 us; speedup vs baseline: 1.1671x; 1.1671x over previous
//
#include <hip/hip_runtime.h>
#include <hip/hip_bf16.h>

// Problem constants: B=8, S=1024, E=1024, H=16, D=64
#define PB 8
#define PS 1024
#define PE 1024
#define PH 16
#define PD 64
#define EPSLN 1e-3f
// softmax scale folded into Wq: SCALE * log2(e), so P = 2^s directly
#define QSCALE 0.04508422f   // (1/32) * 1.4426950408889634

typedef __attribute__((ext_vector_type(8))) short bf16x8;    // 8 bf16 = 4 VGPR
typedef __attribute__((ext_vector_type(4))) float f32x4;
typedef __attribute__((ext_vector_type(16))) float f32x16;

__device__ __forceinline__ unsigned short f2bf(float f) {
    unsigned int u = __float_as_uint(f);
    u += 0x7FFFu + ((u >> 16) & 1u);   // RNE
    return (unsigned short)(u >> 16);
}

__device__ __forceinline__ void gload_lds16(const void* g, void* l) {
    __builtin_amdgcn_global_load_lds(
        (const __attribute__((address_space(1))) unsigned int*)g,
        (__attribute__((address_space(3))) unsigned int*)l,
        16, 0, 0);
}

__device__ __forceinline__ unsigned int cvtpk_bf16(float lo, float hi) {
    unsigned int r;
    asm("v_cvt_pk_bf16_f32 %0, %1, %2" : "=v"(r) : "v"(lo), "v"(hi));
    return r;
}

__device__ __forceinline__ void plswap(unsigned int& a, unsigned int& b) {
    asm("v_permlane32_swap_b32 %0, %1" : "+v"(a), "+v"(b));
}

// LDS chunk swizzle for attn (measured 0 conflicts, r5)
#define SWZF(row, chunk) (((chunk) ^ ((row) & 7) ^ (((row) >> 3) & 3)))

// ---------------------------------------------------------------------------
// Convert X f32 -> bf16 (8M elems, 8 per thread)
// ---------------------------------------------------------------------------
__global__ __launch_bounds__(256) void conv_x(
    const float* __restrict__ X, unsigned short* __restrict__ Xb)
{
    const size_t i = (size_t)blockIdx.x * 256 + threadIdx.x;
    const float4* p = reinterpret_cast<const float4*>(X) + i * 2;
    float4 a = p[0], b = p[1];
    unsigned short r[8];
    r[0] = f2bf(a.x); r[1] = f2bf(a.y); r[2] = f2bf(a.z); r[3] = f2bf(a.w);
    r[4] = f2bf(b.x); r[5] = f2bf(b.y); r[6] = f2bf(b.z); r[7] = f2bf(b.w);
    *reinterpret_cast<uint4*>(Xb + i * 8) = *reinterpret_cast<const uint4*>(r);
}

// ---------------------------------------------------------------------------
// Transpose+convert W's: Wtb[proj*1024 + n][k] = W_proj[k][n] as bf16.
// Wq is pre-scaled by QSCALE (softmax scale * log2e) in f32 — free at runtime.
// ---------------------------------------------------------------------------
__global__ __launch_bounds__(256) void conv_w(
    const float* __restrict__ Wq, const float* __restrict__ Wk,
    const float* __restrict__ Wv, unsigned short* __restrict__ Wtb)
{
    const int proj = blockIdx.z;
    const float* W = (proj == 0) ? Wq : (proj == 1) ? Wk : Wv;
    const float sc = (proj == 0) ? QSCALE : 1.0f;
    __shared__ float tile[32][33];
    const int n0 = blockIdx.x * 32, k0 = blockIdx.y * 32;
    const int tx = threadIdx.x & 31, ty = threadIdx.x >> 5;  // 32 x 8
#pragma unroll
    for (int i = 0; i < 4; ++i)
        tile[ty + i * 8][tx] = W[(size_t)(k0 + ty + i * 8) * PE + n0 + tx];
    __syncthreads();
#pragma unroll
    for (int i = 0; i < 4; ++i)
        Wtb[(size_t)(proj * 1024 + n0 + ty + i * 8) * 1024 + k0 + tx] =
            f2bf(tile[tx][ty + i * 8] * sc);
}

// ---------------------------------------------------------------------------
// rel f32 -> bf16 table (2047 x 16)
// ---------------------------------------------------------------------------
__global__ __launch_bounds__(256) void conv_rel(
    const float* __restrict__ rel, unsigned short* __restrict__ relbf)
{
    const int i = blockIdx.x * 1024 + threadIdx.x * 4;
#pragma unroll
    for (int k = 0; k < 4; ++k)
        if (i + k < (2 * PS - 1) * PH) relbf[i + k] = f2bf(rel[i + k]);
}

// ---------------------------------------------------------------------------
// QKV GEMM: C[8192][3072] bf16 = Xb[8192][1024] @ Wtb^T, MFMA 16x16x32 bf16.
// 128x128 tile, BK=64, 4 waves (2x2), m97 structure — measured ~57us (r5).
// (r6's 256x256 deep-pipeline attempt regressed to 112us: 1 block/CU killed
//  the inter-block overlap the m97 structure relies on. Reverted.)
// ---------------------------------------------------------------------------
__global__ __launch_bounds__(256) void qkv_mfma(
    const unsigned short* __restrict__ Xb,
    const unsigned short* __restrict__ Wtb,
    unsigned short* __restrict__ QKV)
{
    const int orig = blockIdx.x;
    const int wg = (orig & 7) * 192 + (orig >> 3);
    const int nblk = wg % 24, mblk = wg / 24;
    const int m0 = mblk * 128, n0 = nblk * 128;

    __shared__ __align__(16) unsigned short As[128 * 64];
    __shared__ __align__(16) unsigned short Bs[128 * 64];

    const int t = threadIdx.x;
    const int w = t >> 6, l = t & 63;
    const int lane15 = l & 15, lhi = l >> 4;
    const int wm = w >> 1, wn = w & 1;

    f32x4 acc[4][4] = {};

    for (int k0 = 0; k0 < 1024; k0 += 64) {
        __syncthreads();
#pragma unroll
        for (int c = 0; c < 4; ++c) {
            const int ci = (w * 4 + c) * 64 + l;
            const int r = ci >> 3;
            const int srccl = (ci & 7) ^ (r & 7);
            gload_lds16(Xb  + (size_t)(m0 + r) * 1024 + k0 + srccl * 8, &As[ci * 8]);
            gload_lds16(Wtb + (size_t)(n0 + r) * 1024 + k0 + srccl * 8, &Bs[ci * 8]);
        }
        __syncthreads();
#pragma unroll
        for (int kk = 0; kk < 2; ++kk) {
            bf16x8 af[4], bf[4];
#pragma unroll
            for (int mi = 0; mi < 4; ++mi) {
                const int row = wm * 64 + mi * 16 + lane15;
                af[mi] = *reinterpret_cast<const bf16x8*>(
                    &As[row * 64 + (((kk * 4 + lhi) ^ (row & 7)) << 3)]);
            }
#pragma unroll
            for (int ni = 0; ni < 4; ++ni) {
                const int row = wn * 64 + ni * 16 + lane15;
                bf[ni] = *reinterpret_cast<const bf16x8*>(
                    &Bs[row * 64 + (((kk * 4 + lhi) ^ (row & 7)) << 3)]);
            }
#pragma unroll
            for (int mi = 0; mi < 4; ++mi)
#pragma unroll
                for (int ni = 0; ni < 4; ++ni)
                    acc[mi][ni] = __builtin_amdgcn_mfma_f32_16x16x32_bf16(
                        af[mi], bf[ni], acc[mi][ni], 0, 0, 0);
        }
    }
#pragma unroll
    for (int mi = 0; mi < 4; ++mi)
#pragma unroll
        for (int ni = 0; ni < 4; ++ni)
#pragma unroll
            for (int r = 0; r < 4; ++r) {
                const int gr = m0 + wm * 64 + mi * 16 + lhi * 4 + r;
                const int gc = n0 + wn * 64 + ni * 16 + lane15;
                QKV[(size_t)gr * 3072 + gc] = f2bf(acc[mi][ni][r]);
            }
}

// ---------------------------------------------------------------------------
// V transpose: VT[h][b][d][j] = QKV[b*S+j][2048 + h*64 + d]  (bf16, 16 MB)
// ---------------------------------------------------------------------------
__global__ __launch_bounds__(256) void vtrans(
    const unsigned short* __restrict__ QKV, unsigned short* __restrict__ VT)
{
    const int j0 = blockIdx.x * 64, b = blockIdx.y, h = blockIdx.z;
    __shared__ unsigned short tile[64][72];
    const int t = threadIdx.x;

#pragma unroll
    for (int it = 0; it < 2; ++it) {
        const int jr = it * 32 + (t >> 3), dc = t & 7;
        uint4 d = *reinterpret_cast<const uint4*>(
            QKV + ((size_t)(b * PS + j0 + jr)) * 3072 + 2048 + h * 64 + dc * 8);
        *reinterpret_cast<uint4*>(&tile[jr][dc * 8]) = d;
    }
    __syncthreads();
    const int d = t & 63, jc = t >> 6;
    unsigned short out[16];
#pragma unroll
    for (int k = 0; k < 16; ++k) out[k] = tile[jc * 16 + k][d];
    unsigned short* dst = VT + ((size_t)((h * 8 + b) * 64 + d)) * 1024 + j0 + jc * 16;
    *reinterpret_cast<uint4*>(dst)     = *reinterpret_cast<const uint4*>(out);
    *reinterpret_cast<uint4*>(dst + 8) = *reinterpret_cast<const uint4*>(out + 8);
}

// ---------------------------------------------------------------------------
// Fused attention, 32x32x16 MFMA, swapped QK^T, in-register softmax (T12),
// fused bias.V, row-sum via ones-MFMA.  Block = 4 waves x 32 q = 128 q-rows.
// Q pre-scaled so P = 2^s (single v_exp_f32, no muls).
// ---------------------------------------------------------------------------
__global__ __launch_bounds__(256) void attn_mfma(
    const unsigned short* __restrict__ qkv,
    const unsigned short* __restrict__ VT,
    const unsigned short* __restrict__ relbf,
    float* __restrict__ O)
{
    __shared__ __align__(16) unsigned short Ks[2][64 * 64];  // [j][d] swizzled
    __shared__ __align__(16) unsigned short Vt[2][64 * 64];  // [d][j] swizzled

    const int orig = blockIdx.x;                   // 1024 blocks
    const int wg = (orig & 7) * 128 + (orig >> 3); // XCD-chunked, bijective
    const int qt = wg & 7;
    const int h  = (wg >> 3) & 15;
    const int b  = wg >> 7;

    const int t = threadIdx.x;
    const int w = t >> 6, l = t & 63;
    const int lane31 = l & 31, hi = l >> 5;

    const int qrow_g = qt * 128 + w * 32 + lane31;   // query index i (0..1023)

    // Q fragments (B-operand of swapped QK): col=q=lane31, k=hi*8+e
    bf16x8 qf[4];
    {
        const unsigned short* qp =
            qkv + ((size_t)(b * PS) + qrow_g) * 3072 + h * 64 + hi * 8;
#pragma unroll
        for (int dw = 0; dw < 4; ++dw)
            qf[dw] = *reinterpret_cast<const bf16x8*>(qp + dw * 16);
    }

    const unsigned short* Kg = qkv + (size_t)(b * PS) * 3072 + 1024 + h * 64;
    const unsigned short* Vg = VT + ((size_t)((h * 8 + b) * 64)) * 1024;

    // hoisted bias-table pointer: af[jw] at tile tt = relp + tt*64 + jw*16
    const int s1 = (h << 6) | (qrow_g >> 4);
    const int s2hi = (qrow_g & 15) << 6;
    const unsigned short* relp = relbf + (size_t)(s2hi - s1 + PS - 1) * PH + hi * 8;

    f32x16 accP[2] = {};
    f32x16 accB[2] = {};
    f32x16 accL = {};
    bf16x8 ones;
#pragma unroll
    for (int i = 0; i < 8; ++i) ones[i] = (short)0x3F80;  // bf16 1.0

#define ATTN_STAGE(buf, j0)                                                          \
    {                                                                                \
        _Pragma("unroll")                                                            \
        for (int it = 0; it < 2; ++it) {                                             \
            const int ci = it * 256 + t;                                             \
            const int r = ci >> 3;                                                   \
            const int scl = SWZF(r, ci & 7);                                         \
            gload_lds16(Kg + (size_t)((j0) + r) * 3072 + scl * 8, &Ks[buf][ci * 8]); \
            gload_lds16(Vg + (size_t)r * 1024 + (j0) + scl * 8, &Vt[buf][ci * 8]);   \
        }                                                                            \
    }

    ATTN_STAGE(0, 0)

    for (int tt = 0; tt < 16; ++tt) {
        const int cur = tt & 1;
        const int j0 = tt * 64;

        // bias A-frags: 16 contiguous bf16 from relbf (L2-resident)
        bf16x8 af[4];
        __builtin_amdgcn_sched_barrier(0);
#pragma unroll
        for (int jw = 0; jw < 4; ++jw)
            af[jw] = *reinterpret_cast<const bf16x8*>(relp + j0 + jw * 16);
        __builtin_amdgcn_sched_barrier(0);
        if (tt < 15) {
            ATTN_STAGE(cur ^ 1, j0 + 64)
            __builtin_amdgcn_sched_barrier(0);
            asm volatile("s_waitcnt vmcnt(8)" ::: "memory");  // cur tile staged
        } else {
            asm volatile("s_waitcnt vmcnt(4)" ::: "memory");
        }
        __builtin_amdgcn_sched_barrier(0);
        __builtin_amdgcn_s_barrier();
        __builtin_amdgcn_sched_barrier(0);

        // --- QK^T (swapped): S^T[j][q], then 2^s -> P fragments in-register ---
        bf16x8 pfrag[4];
#pragma unroll
        for (int jt = 0; jt < 2; ++jt) {
            f32x16 sc = {};
            __builtin_amdgcn_s_setprio(1);
#pragma unroll
            for (int dw = 0; dw < 4; ++dw) {
                const int row = jt * 32 + lane31;
                bf16x8 aK = *reinterpret_cast<const bf16x8*>(
                    &Ks[cur][row * 64 + (SWZF(row, dw * 2 + hi) << 3)]);
                sc = __builtin_amdgcn_mfma_f32_32x32x16_bf16(aK, qf[dw], sc, 0, 0, 0);
            }
            __builtin_amdgcn_s_setprio(0);
            // lane holds S^T[j = jt*32 + 4*(2*(r>>2)+hi) + (r&3)][q=lane31]
            float p[16];
#pragma unroll
            for (int r = 0; r < 16; ++r) p[r] = exp2f(sc[r]);  // Q pre-scaled
            unsigned int a0 = cvtpk_bf16(p[0],  p[1]),  a1 = cvtpk_bf16(p[2],  p[3]);
            unsigned int b0 = cvtpk_bf16(p[4],  p[5]),  b1 = cvtpk_bf16(p[6],  p[7]);
            unsigned int c0 = cvtpk_bf16(p[8],  p[9]),  c1 = cvtpk_bf16(p[10], p[11]);
            unsigned int d0 = cvtpk_bf16(p[12], p[13]), d1 = cvtpk_bf16(p[14], p[15]);
            plswap(a0, b0); plswap(a1, b1);   // win0: quads (2hi, 2hi+1)
            plswap(c0, d0); plswap(c1, d1);   // win1: quads (4+2hi, 5+2hi)
            union { unsigned int u[4]; bf16x8 v; } pk0, pk1;
            pk0.u[0] = a0; pk0.u[1] = a1; pk0.u[2] = b0; pk0.u[3] = b1;
            pk1.u[0] = c0; pk1.u[1] = c1; pk1.u[2] = d0; pk1.u[3] = d1;
            pfrag[jt * 2]     = pk0.v;
            pfrag[jt * 2 + 1] = pk1.v;
        }

        // --- PV + bias.V + row-sum: V fragment loaded once, used by both chains
        __builtin_amdgcn_s_setprio(1);
#pragma unroll
        for (int jw = 0; jw < 4; ++jw) {
            accL = __builtin_amdgcn_mfma_f32_32x32x16_bf16(pfrag[jw], ones, accL, 0, 0, 0);
#pragma unroll
            for (int dt = 0; dt < 2; ++dt) {
                const int row = dt * 32 + lane31;
                bf16x8 bV = *reinterpret_cast<const bf16x8*>(
                    &Vt[cur][row * 64 + (SWZF(row, jw * 2 + hi) << 3)]);
                accP[dt] = __builtin_amdgcn_mfma_f32_32x32x16_bf16(
                    pfrag[jw], bV, accP[dt], 0, 0, 0);
                accB[dt] = __builtin_amdgcn_mfma_f32_32x32x16_bf16(
                    af[jw], bV, accB[dt], 0, 0, 0);
            }
        }
        __builtin_amdgcn_s_setprio(0);
        __builtin_amdgcn_s_barrier();
    }
#undef ATTN_STAGE

    // accL[r] = l[q-row rl] replicated across all lanes of the row's quads
#pragma unroll
    for (int dt = 0; dt < 2; ++dt)
#pragma unroll
        for (int r = 0; r < 16; ++r) {
            const int rl = (r & 3) + 8 * (r >> 2) + 4 * hi;   // q-row local
            O[((size_t)(b * PS + qt * 128 + w * 32 + rl)) * PE + h * 64 + dt * 32 + lane31]
                = accP[dt][r] / accL[r] + accB[dt][r];
        }
}

// ---------------------------------------------------------------------------
// LayerNorm over last dim (1024), in-place on d_out.
// ---------------------------------------------------------------------------
__global__ __launch_bounds__(256) void layernorm_inplace(
    float* __restrict__ O,
    const float* __restrict__ gamma,
    const float* __restrict__ beta)
{
    const int row = blockIdx.x;
    float* p = O + (size_t)row * PE;
    const int t = threadIdx.x;

    float4 x = reinterpret_cast<float4*>(p)[t];
    float s  = x.x + x.y + x.z + x.w;
    float s2 = x.x * x.x + x.y * x.y + x.z * x.z + x.w * x.w;

#pragma unroll
    for (int off = 1; off < 64; off <<= 1) {
        s  += __shfl_xor(s, off, 64);
        s2 += __shfl_xor(s2, off, 64);
    }
    __shared__ float red[2][4];
    const int wid = t >> 6;
    if ((t & 63) == 0) { red[0][wid] = s; red[1][wid] = s2; }
    __syncthreads();
    const float ts  = red[0][0] + red[0][1] + red[0][2] + red[0][3];
    const float ts2 = red[1][0] + red[1][1] + red[1][2] + red[1][3];

    const float mu  = ts * (1.f / PE);
    const float var = ts2 * (1.f / PE) - mu * mu;
    const float inv = rsqrtf(var + EPSLN);

    const float4 g  = reinterpret_cast<const float4*>(gamma)[t];
    const float4 bb = reinterpret_cast<const float4*>(beta)[t];
    float4 y;
    y.x = (x.x - mu) * inv * g.x + bb.x;
    y.y = (x.y - mu) * inv * g.y + bb.y;
    y.z = (x.z - mu) * inv * g.z + bb.z;
    y.w = (x.w - mu) * inv * g.w + bb.w;
    reinterpret_cast<float4*>(p)[t] = y;
}

// ---------------------------------------------------------------------------
extern "C" void kernel_launch(void* const* d_in, const int* in_sizes, int n_in,
                              void* d_out, int out_size, void* d_ws, size_t ws_size,
                              hipStream_t stream) {
    (void)in_sizes; (void)n_in; (void)out_size; (void)ws_size;
    const float* x     = (const float*)d_in[0];
    const float* Wq    = (const float*)d_in[1];
    const float* Wk    = (const float*)d_in[2];
    const float* Wv    = (const float*)d_in[3];
    const float* rel   = (const float*)d_in[4];
    const float* gamma = (const float*)d_in[5];
    const float* beta  = (const float*)d_in[6];
    float* out = (float*)d_out;

    char* ws = (char*)d_ws;
    // Layout (86 MB): [Xb 16MB | Wtb 6MB | QKV 48MB | VT 16MB]
    // relbf (64KB) aliases Xb region: Xb dead after qkv_mfma; conv_rel runs after.
    unsigned short* Xb    = (unsigned short*)ws;
    unsigned short* Wtb   = (unsigned short*)(ws + 16777216);
    unsigned short* QKV   = (unsigned short*)(ws + 23068672);
    unsigned short* VT    = (unsigned short*)(ws + 73400320);
    unsigned short* relbf = (unsigned short*)ws;

    conv_x<<<4096, 256, 0, stream>>>(x, Xb);
    conv_w<<<dim3(32, 32, 3), 256, 0, stream>>>(Wq, Wk, Wv, Wtb);
    qkv_mfma<<<1536, 256, 0, stream>>>(Xb, Wtb, QKV);
    conv_rel<<<32, 256, 0, stream>>>(rel, relbf);
    vtrans<<<dim3(16, 8, 16), 256, 0, stream>>>(QKV, VT);
    attn_mfma<<<1024, 256, 0, stream>>>(QKV, VT, relbf, out);
    layernorm_inplace<<<PB * PS, 256, 0, stream>>>(out, gamma, beta);
}

// Round 8
// 169.227 us; speedup vs baseline: 1.2520x; 1.0727x over previous
//
#include <hip/hip_runtime.h>
#include <hip/hip_bf16.h>

// Problem constants: B=8, S=1024, E=1024, H=16, D=64
#define PB 8
#define PS 1024
#define PE 1024
#define PH 16
#define PD 64
#define EPSLN 1e-3f
// softmax scale folded into Wq: SCALE * log2(e), so P = 2^s via raw v_exp_f32
#define QSCALE 0.04508422f   // (1/32) * 1.4426950408889634

typedef __attribute__((ext_vector_type(8))) short bf16x8;    // 8 bf16 = 4 VGPR
typedef __attribute__((ext_vector_type(4))) float f32x4;
typedef __attribute__((ext_vector_type(16))) float f32x16;

__device__ __forceinline__ unsigned short f2bf(float f) {
    unsigned int u = __float_as_uint(f);
    u += 0x7FFFu + ((u >> 16) & 1u);   // RNE
    return (unsigned short)(u >> 16);
}

__device__ __forceinline__ void gload_lds16(const void* g, void* l) {
    __builtin_amdgcn_global_load_lds(
        (const __attribute__((address_space(1))) unsigned int*)g,
        (__attribute__((address_space(3))) unsigned int*)l,
        16, 0, 0);
}

__device__ __forceinline__ unsigned int cvtpk_bf16(float lo, float hi) {
    unsigned int r;
    asm("v_cvt_pk_bf16_f32 %0, %1, %2" : "=v"(r) : "v"(lo), "v"(hi));
    return r;
}

__device__ __forceinline__ void plswap(unsigned int& a, unsigned int& b) {
    asm("v_permlane32_swap_b32 %0, %1" : "+v"(a), "+v"(b));
}

// raw hardware 2^x — no OCML denormal fix-up (inputs are |x| <~ 32 here)
__device__ __forceinline__ float exp2_raw(float x) {
    float r;
    asm("v_exp_f32 %0, %1" : "=v"(r) : "v"(x));
    return r;
}

// LDS chunk swizzle for attn (measured 0 conflicts, r5)
#define SWZF(row, chunk) (((chunk) ^ ((row) & 7) ^ (((row) >> 3) & 3)))

// ---------------------------------------------------------------------------
// Convert X f32 -> bf16 (8M elems, 8 per thread)
// ---------------------------------------------------------------------------
__global__ __launch_bounds__(256) void conv_x(
    const float* __restrict__ X, unsigned short* __restrict__ Xb)
{
    const size_t i = (size_t)blockIdx.x * 256 + threadIdx.x;
    const float4* p = reinterpret_cast<const float4*>(X) + i * 2;
    float4 a = p[0], b = p[1];
    unsigned short r[8];
    r[0] = f2bf(a.x); r[1] = f2bf(a.y); r[2] = f2bf(a.z); r[3] = f2bf(a.w);
    r[4] = f2bf(b.x); r[5] = f2bf(b.y); r[6] = f2bf(b.z); r[7] = f2bf(b.w);
    *reinterpret_cast<uint4*>(Xb + i * 8) = *reinterpret_cast<const uint4*>(r);
}

// ---------------------------------------------------------------------------
// Transpose+convert W's: Wtb[proj*1024 + n][k] = W_proj[k][n] as bf16.
// Wq is pre-scaled by QSCALE (softmax scale * log2e) in f32 — free at runtime.
// ---------------------------------------------------------------------------
__global__ __launch_bounds__(256) void conv_w(
    const float* __restrict__ Wq, const float* __restrict__ Wk,
    const float* __restrict__ Wv, unsigned short* __restrict__ Wtb)
{
    const int proj = blockIdx.z;
    const float* W = (proj == 0) ? Wq : (proj == 1) ? Wk : Wv;
    const float sc = (proj == 0) ? QSCALE : 1.0f;
    __shared__ float tile[32][33];
    const int n0 = blockIdx.x * 32, k0 = blockIdx.y * 32;
    const int tx = threadIdx.x & 31, ty = threadIdx.x >> 5;  // 32 x 8
#pragma unroll
    for (int i = 0; i < 4; ++i)
        tile[ty + i * 8][tx] = W[(size_t)(k0 + ty + i * 8) * PE + n0 + tx];
    __syncthreads();
#pragma unroll
    for (int i = 0; i < 4; ++i)
        Wtb[(size_t)(proj * 1024 + n0 + ty + i * 8) * 1024 + k0 + tx] =
            f2bf(tile[tx][ty + i * 8] * sc);
}

// ---------------------------------------------------------------------------
// rel f32 -> bf16 table (2047 x 16)
// ---------------------------------------------------------------------------
__global__ __launch_bounds__(256) void conv_rel(
    const float* __restrict__ rel, unsigned short* __restrict__ relbf)
{
    const int i = blockIdx.x * 1024 + threadIdx.x * 4;
#pragma unroll
    for (int k = 0; k < 4; ++k)
        if (i + k < (2 * PS - 1) * PH) relbf[i + k] = f2bf(rel[i + k]);
}

// ---------------------------------------------------------------------------
// QKV GEMM: C[8192][3072] bf16 = Xb[8192][1024] @ Wtb^T, MFMA 16x16x32 bf16.
// 128x128 tile, BK=64, 4 waves (2x2), m97 structure — measured ~57us (r5).
// ---------------------------------------------------------------------------
__global__ __launch_bounds__(256) void qkv_mfma(
    const unsigned short* __restrict__ Xb,
    const unsigned short* __restrict__ Wtb,
    unsigned short* __restrict__ QKV)
{
    const int orig = blockIdx.x;
    const int wg = (orig & 7) * 192 + (orig >> 3);
    const int nblk = wg % 24, mblk = wg / 24;
    const int m0 = mblk * 128, n0 = nblk * 128;

    __shared__ __align__(16) unsigned short As[128 * 64];
    __shared__ __align__(16) unsigned short Bs[128 * 64];

    const int t = threadIdx.x;
    const int w = t >> 6, l = t & 63;
    const int lane15 = l & 15, lhi = l >> 4;
    const int wm = w >> 1, wn = w & 1;

    f32x4 acc[4][4] = {};

    for (int k0 = 0; k0 < 1024; k0 += 64) {
        __syncthreads();
#pragma unroll
        for (int c = 0; c < 4; ++c) {
            const int ci = (w * 4 + c) * 64 + l;
            const int r = ci >> 3;
            const int srccl = (ci & 7) ^ (r & 7);
            gload_lds16(Xb  + (size_t)(m0 + r) * 1024 + k0 + srccl * 8, &As[ci * 8]);
            gload_lds16(Wtb + (size_t)(n0 + r) * 1024 + k0 + srccl * 8, &Bs[ci * 8]);
        }
        __syncthreads();
#pragma unroll
        for (int kk = 0; kk < 2; ++kk) {
            bf16x8 af[4], bf[4];
#pragma unroll
            for (int mi = 0; mi < 4; ++mi) {
                const int row = wm * 64 + mi * 16 + lane15;
                af[mi] = *reinterpret_cast<const bf16x8*>(
                    &As[row * 64 + (((kk * 4 + lhi) ^ (row & 7)) << 3)]);
            }
#pragma unroll
            for (int ni = 0; ni < 4; ++ni) {
                const int row = wn * 64 + ni * 16 + lane15;
                bf[ni] = *reinterpret_cast<const bf16x8*>(
                    &Bs[row * 64 + (((kk * 4 + lhi) ^ (row & 7)) << 3)]);
            }
#pragma unroll
            for (int mi = 0; mi < 4; ++mi)
#pragma unroll
                for (int ni = 0; ni < 4; ++ni)
                    acc[mi][ni] = __builtin_amdgcn_mfma_f32_16x16x32_bf16(
                        af[mi], bf[ni], acc[mi][ni], 0, 0, 0);
        }
    }
#pragma unroll
    for (int mi = 0; mi < 4; ++mi)
#pragma unroll
        for (int ni = 0; ni < 4; ++ni)
#pragma unroll
            for (int r = 0; r < 4; ++r) {
                const int gr = m0 + wm * 64 + mi * 16 + lhi * 4 + r;
                const int gc = n0 + wn * 64 + ni * 16 + lane15;
                QKV[(size_t)gr * 3072 + gc] = f2bf(acc[mi][ni][r]);
            }
}

// ---------------------------------------------------------------------------
// V transpose: VT[h][b][d][j] = QKV[b*S+j][2048 + h*64 + d]  (bf16, 16 MB)
// ---------------------------------------------------------------------------
__global__ __launch_bounds__(256) void vtrans(
    const unsigned short* __restrict__ QKV, unsigned short* __restrict__ VT)
{
    const int j0 = blockIdx.x * 64, b = blockIdx.y, h = blockIdx.z;
    __shared__ unsigned short tile[64][72];
    const int t = threadIdx.x;

#pragma unroll
    for (int it = 0; it < 2; ++it) {
        const int jr = it * 32 + (t >> 3), dc = t & 7;
        uint4 d = *reinterpret_cast<const uint4*>(
            QKV + ((size_t)(b * PS + j0 + jr)) * 3072 + 2048 + h * 64 + dc * 8);
        *reinterpret_cast<uint4*>(&tile[jr][dc * 8]) = d;
    }
    __syncthreads();
    const int d = t & 63, jc = t >> 6;
    unsigned short out[16];
#pragma unroll
    for (int k = 0; k < 16; ++k) out[k] = tile[jc * 16 + k][d];
    unsigned short* dst = VT + ((size_t)((h * 8 + b) * 64 + d)) * 1024 + j0 + jc * 16;
    *reinterpret_cast<uint4*>(dst)     = *reinterpret_cast<const uint4*>(out);
    *reinterpret_cast<uint4*>(dst + 8) = *reinterpret_cast<const uint4*>(out + 8);
}

// ---------------------------------------------------------------------------
// Fused attention, 32x32x16 MFMA, swapped QK^T, in-register softmax (T12),
// fused bias.V, row-sum via ones-MFMA.  Block = 4 waves x 32 q = 128 q-rows.
// Tile body is sm-split for MFMA/VALU overlap:
//   QK0,QK1 -> SM0 (overlaps QK1 exec) -> PV(jw0,1) -> SM1 (overlaps PV exec)
//   -> PV(jw2,3)
// ---------------------------------------------------------------------------
__global__ __launch_bounds__(256) void attn_mfma(
    const unsigned short* __restrict__ qkv,
    const unsigned short* __restrict__ VT,
    const unsigned short* __restrict__ relbf,
    float* __restrict__ O)
{
    __shared__ __align__(16) unsigned short Ks[2][64 * 64];  // [j][d] swizzled
    __shared__ __align__(16) unsigned short Vt[2][64 * 64];  // [d][j] swizzled

    const int orig = blockIdx.x;                   // 1024 blocks
    const int wg = (orig & 7) * 128 + (orig >> 3); // XCD-chunked, bijective
    const int qt = wg & 7;
    const int h  = (wg >> 3) & 15;
    const int b  = wg >> 7;

    const int t = threadIdx.x;
    const int w = t >> 6, l = t & 63;
    const int lane31 = l & 31, hi = l >> 5;

    const int qrow_g = qt * 128 + w * 32 + lane31;   // query index i (0..1023)

    // Q fragments (B-operand of swapped QK): col=q=lane31, k=hi*8+e
    bf16x8 qf[4];
    {
        const unsigned short* qp =
            qkv + ((size_t)(b * PS) + qrow_g) * 3072 + h * 64 + hi * 8;
#pragma unroll
        for (int dw = 0; dw < 4; ++dw)
            qf[dw] = *reinterpret_cast<const bf16x8*>(qp + dw * 16);
    }

    const unsigned short* Kg = qkv + (size_t)(b * PS) * 3072 + 1024 + h * 64;
    const unsigned short* Vg = VT + ((size_t)((h * 8 + b) * 64)) * 1024;

    // hoisted bias-table pointer: af[jw] at tile tt = relp + tt*64 + jw*16
    const int s1 = (h << 6) | (qrow_g >> 4);
    const int s2hi = (qrow_g & 15) << 6;
    const unsigned short* relp = relbf + (size_t)(s2hi - s1 + PS - 1) * PH + hi * 8;

    f32x16 accP[2] = {};
    f32x16 accB[2] = {};
    f32x16 accL = {};
    bf16x8 ones;
#pragma unroll
    for (int i = 0; i < 8; ++i) ones[i] = (short)0x3F80;  // bf16 1.0

#define ATTN_STAGE(buf, j0)                                                          \
    {                                                                                \
        _Pragma("unroll")                                                            \
        for (int it = 0; it < 2; ++it) {                                             \
            const int ci = it * 256 + t;                                             \
            const int r = ci >> 3;                                                   \
            const int scl = SWZF(r, ci & 7);                                         \
            gload_lds16(Kg + (size_t)((j0) + r) * 3072 + scl * 8, &Ks[buf][ci * 8]); \
            gload_lds16(Vg + (size_t)r * 1024 + (j0) + scl * 8, &Vt[buf][ci * 8]);   \
        }                                                                            \
    }

    // softmax-finish for one 32-j half: sc -> two bf16x8 P fragments
#define SM_FINISH(sc, pfA, pfB)                                                      \
    {                                                                                \
        float p[16];                                                                 \
        _Pragma("unroll")                                                            \
        for (int r = 0; r < 16; ++r) p[r] = exp2_raw((sc)[r]);                       \
        unsigned int a0 = cvtpk_bf16(p[0],  p[1]),  a1 = cvtpk_bf16(p[2],  p[3]);    \
        unsigned int b0 = cvtpk_bf16(p[4],  p[5]),  b1 = cvtpk_bf16(p[6],  p[7]);    \
        unsigned int c0 = cvtpk_bf16(p[8],  p[9]),  c1 = cvtpk_bf16(p[10], p[11]);   \
        unsigned int d0 = cvtpk_bf16(p[12], p[13]), d1 = cvtpk_bf16(p[14], p[15]);   \
        plswap(a0, b0); plswap(a1, b1);                                              \
        plswap(c0, d0); plswap(c1, d1);                                              \
        union { unsigned int u[4]; bf16x8 v; } pk0, pk1;                             \
        pk0.u[0] = a0; pk0.u[1] = a1; pk0.u[2] = b0; pk0.u[3] = b1;                  \
        pk1.u[0] = c0; pk1.u[1] = c1; pk1.u[2] = d0; pk1.u[3] = d1;                  \
        (pfA) = pk0.v; (pfB) = pk1.v;                                                \
    }

    // PV + bias.V + row-sum for one 16-j slot jw with P fragment pf
#define PV_STEP(jw, pf)                                                              \
    {                                                                                \
        accL = __builtin_amdgcn_mfma_f32_32x32x16_bf16((pf), ones, accL, 0, 0, 0);   \
        _Pragma("unroll")                                                            \
        for (int dt = 0; dt < 2; ++dt) {                                             \
            const int row = dt * 32 + lane31;                                        \
            bf16x8 bV = *reinterpret_cast<const bf16x8*>(                            \
                &Vt[cur][row * 64 + (SWZF(row, (jw) * 2 + hi) << 3)]);               \
            accP[dt] = __builtin_amdgcn_mfma_f32_32x32x16_bf16(                      \
                (pf), bV, accP[dt], 0, 0, 0);                                        \
            accB[dt] = __builtin_amdgcn_mfma_f32_32x32x16_bf16(                      \
                af[jw], bV, accB[dt], 0, 0, 0);                                      \
        }                                                                            \
    }

    ATTN_STAGE(0, 0)

    for (int tt = 0; tt < 16; ++tt) {
        const int cur = tt & 1;
        const int j0 = tt * 64;

        // bias A-frags: 16 contiguous bf16 from relbf (L2-resident)
        bf16x8 af[4];
        __builtin_amdgcn_sched_barrier(0);
#pragma unroll
        for (int jw = 0; jw < 4; ++jw)
            af[jw] = *reinterpret_cast<const bf16x8*>(relp + j0 + jw * 16);
        __builtin_amdgcn_sched_barrier(0);
        if (tt < 15) {
            ATTN_STAGE(cur ^ 1, j0 + 64)
            __builtin_amdgcn_sched_barrier(0);
            asm volatile("s_waitcnt vmcnt(8)" ::: "memory");  // cur tile staged
        } else {
            asm volatile("s_waitcnt vmcnt(4)" ::: "memory");
        }
        __builtin_amdgcn_sched_barrier(0);
        __builtin_amdgcn_s_barrier();
        __builtin_amdgcn_sched_barrier(0);

        // --- QK^T both halves (8 MFMAs issued back-to-back) ---
        f32x16 sc0 = {}, sc1 = {};
        __builtin_amdgcn_s_setprio(1);
#pragma unroll
        for (int dw = 0; dw < 4; ++dw) {
            const int row = lane31;
            bf16x8 aK = *reinterpret_cast<const bf16x8*>(
                &Ks[cur][row * 64 + (SWZF(row, dw * 2 + hi) << 3)]);
            sc0 = __builtin_amdgcn_mfma_f32_32x32x16_bf16(aK, qf[dw], sc0, 0, 0, 0);
        }
#pragma unroll
        for (int dw = 0; dw < 4; ++dw) {
            const int row = 32 + lane31;
            bf16x8 aK = *reinterpret_cast<const bf16x8*>(
                &Ks[cur][row * 64 + (SWZF(row, dw * 2 + hi) << 3)]);
            sc1 = __builtin_amdgcn_mfma_f32_32x32x16_bf16(aK, qf[dw], sc1, 0, 0, 0);
        }
        __builtin_amdgcn_s_setprio(0);

        // --- SM0 (VALU; overlaps QK1 MFMA execution) ---
        bf16x8 pf0, pf1, pf2, pf3;
        SM_FINISH(sc0, pf0, pf1)

        // --- PV first half ---
        __builtin_amdgcn_s_setprio(1);
        PV_STEP(0, pf0)
        PV_STEP(1, pf1)
        __builtin_amdgcn_s_setprio(0);

        // --- SM1 (VALU; overlaps PV MFMA execution) ---
        SM_FINISH(sc1, pf2, pf3)

        // --- PV second half ---
        __builtin_amdgcn_s_setprio(1);
        PV_STEP(2, pf2)
        PV_STEP(3, pf3)
        __builtin_amdgcn_s_setprio(0);

        __builtin_amdgcn_s_barrier();
    }
#undef ATTN_STAGE
#undef SM_FINISH
#undef PV_STEP

    // accL[r] = l[q-row rl] replicated across all lanes of the row's quads
#pragma unroll
    for (int dt = 0; dt < 2; ++dt)
#pragma unroll
        for (int r = 0; r < 16; ++r) {
            const int rl = (r & 3) + 8 * (r >> 2) + 4 * hi;   // q-row local
            O[((size_t)(b * PS + qt * 128 + w * 32 + rl)) * PE + h * 64 + dt * 32 + lane31]
                = accP[dt][r] / accL[r] + accB[dt][r];
        }
}

// ---------------------------------------------------------------------------
// LayerNorm over last dim (1024), in-place on d_out.
// ---------------------------------------------------------------------------
__global__ __launch_bounds__(256) void layernorm_inplace(
    float* __restrict__ O,
    const float* __restrict__ gamma,
    const float* __restrict__ beta)
{
    const int row = blockIdx.x;
    float* p = O + (size_t)row * PE;
    const int t = threadIdx.x;

    float4 x = reinterpret_cast<float4*>(p)[t];
    float s  = x.x + x.y + x.z + x.w;
    float s2 = x.x * x.x + x.y * x.y + x.z * x.z + x.w * x.w;

#pragma unroll
    for (int off = 1; off < 64; off <<= 1) {
        s  += __shfl_xor(s, off, 64);
        s2 += __shfl_xor(s2, off, 64);
    }
    __shared__ float red[2][4];
    const int wid = t >> 6;
    if ((t & 63) == 0) { red[0][wid] = s; red[1][wid] = s2; }
    __syncthreads();
    const float ts  = red[0][0] + red[0][1] + red[0][2] + red[0][3];
    const float ts2 = red[1][0] + red[1][1] + red[1][2] + red[1][3];

    const float mu  = ts * (1.f / PE);
    const float var = ts2 * (1.f / PE) - mu * mu;
    const float inv = rsqrtf(var + EPSLN);

    const float4 g  = reinterpret_cast<const float4*>(gamma)[t];
    const float4 bb = reinterpret_cast<const float4*>(beta)[t];
    float4 y;
    y.x = (x.x - mu) * inv * g.x + bb.x;
    y.y = (x.y - mu) * inv * g.y + bb.y;
    y.z = (x.z - mu) * inv * g.z + bb.z;
    y.w = (x.w - mu) * inv * g.w + bb.w;
    reinterpret_cast<float4*>(p)[t] = y;
}

// ---------------------------------------------------------------------------
extern "C" void kernel_launch(void* const* d_in, const int* in_sizes, int n_in,
                              void* d_out, int out_size, void* d_ws, size_t ws_size,
                              hipStream_t stream) {
    (void)in_sizes; (void)n_in; (void)out_size; (void)ws_size;
    const float* x     = (const float*)d_in[0];
    const float* Wq    = (const float*)d_in[1];
    const float* Wk    = (const float*)d_in[2];
    const float* Wv    = (const float*)d_in[3];
    const float* rel   = (const float*)d_in[4];
    const float* gamma = (const float*)d_in[5];
    const float* beta  = (const float*)d_in[6];
    float* out = (float*)d_out;

    char* ws = (char*)d_ws;
    // Layout (86 MB): [Xb 16MB | Wtb 6MB | QKV 48MB | VT 16MB]
    // relbf (64KB) aliases Xb region: Xb dead after qkv_mfma; conv_rel runs after.
    unsigned short* Xb    = (unsigned short*)ws;
    unsigned short* Wtb   = (unsigned short*)(ws + 16777216);
    unsigned short* QKV   = (unsigned short*)(ws + 23068672);
    unsigned short* VT    = (unsigned short*)(ws + 73400320);
    unsigned short* relbf = (unsigned short*)ws;

    conv_x<<<4096, 256, 0, stream>>>(x, Xb);
    conv_w<<<dim3(32, 32, 3), 256, 0, stream>>>(Wq, Wk, Wv, Wtb);
    qkv_mfma<<<1536, 256, 0, stream>>>(Xb, Wtb, QKV);
    conv_rel<<<32, 256, 0, stream>>>(rel, relbf);
    vtrans<<<dim3(16, 8, 16), 256, 0, stream>>>(QKV, VT);
    attn_mfma<<<1024, 256, 0, stream>>>(QKV, VT, relbf, out);
    layernorm_inplace<<<PB * PS, 256, 0, stream>>>(out, gamma, beta);
}